// Round 4
// baseline (248.944 us; speedup 1.0000x reference)
//
#include <hip/hip_runtime.h>
#include <hip/hip_fp16.h>

constexpr int N      = 100000;
constexpr int E      = 3200000;
constexpr int IN_CH  = 128;
constexpr int HID    = 16;
constexpr int OUT_CH = 64;

constexpr int NPB    = 128;                  // nodes per bucket
constexpr int NB     = (N + NPB - 1) / NPB;  // 782 buckets
constexpr int PBLK   = 256;                  // partition blocks
constexpr int CHUNK  = (E + PBLK - 1) / PBLK;

// ---- pass A: per-block bucket histogram (no global atomics) ----
__global__ __launch_bounds__(256) void k_hist(const int* __restrict__ ei,
                                              unsigned* __restrict__ pbc) {
    __shared__ unsigned cnt[NB];
    int k = blockIdx.x, t = threadIdx.x;
    for (int b = t; b < NB; b += 256) cnt[b] = 0;
    __syncthreads();
    const int* dst = ei + E;
    int e0 = k * CHUNK, e1 = min(e0 + CHUNK, E);
    for (int e = e0 + t; e < e1; e += 256)
        atomicAdd(&cnt[((unsigned)__builtin_nontemporal_load(dst + e)) >> 7], 1u);
    __syncthreads();
    for (int b = t; b < NB; b += 256) pbc[(size_t)k * NB + b] = cnt[b];
}

// ---- pass B: column scan ----
__global__ __launch_bounds__(256) void k_scan_cols(unsigned* __restrict__ pbc,
                                                   unsigned* __restrict__ tot) {
    __shared__ unsigned s[PBLK];
    int b = blockIdx.x, t = threadIdx.x;
    unsigned v = pbc[(size_t)t * NB + b];
    s[t] = v;
    __syncthreads();
    for (int off = 1; off < PBLK; off <<= 1) {
        unsigned u = (t >= off) ? s[t - off] : 0u;
        __syncthreads();
        s[t] += u;
        __syncthreads();
    }
    pbc[(size_t)t * NB + b] = s[t] - v;      // exclusive
    if (t == PBLK - 1) tot[b] = s[t];
}

// ---- pass C: scan bucket totals ----
__global__ __launch_bounds__(1024) void k_scan_tot(const unsigned* __restrict__ tot,
                                                   unsigned* __restrict__ base) {
    __shared__ unsigned s[1024];
    int t = threadIdx.x;
    unsigned v = (t < NB) ? tot[t] : 0u;
    s[t] = v;
    __syncthreads();
    for (int off = 1; off < 1024; off <<= 1) {
        unsigned u = (t >= off) ? s[t - off] : 0u;
        __syncthreads();
        s[t] += u;
        __syncthreads();
    }
    if (t < NB) base[t] = s[t] - v;
    if (t == 1023) base[NB] = s[t];
}

// ---- pass D: partition edges into buckets ----
__global__ __launch_bounds__(256) void k_partition(const int* __restrict__ ei,
                                                   const unsigned* __restrict__ pbc,
                                                   const unsigned* __restrict__ base,
                                                   unsigned* __restrict__ packed) {
    __shared__ unsigned gcur[NB];
    int k = blockIdx.x, t = threadIdx.x;
    for (int b = t; b < NB; b += 256)
        gcur[b] = base[b] + pbc[(size_t)k * NB + b];
    __syncthreads();
    int e0 = k * CHUNK, e1 = min(e0 + CHUNK, E);
    for (int e = e0 + t; e < e1; e += 256) {
        unsigned s = (unsigned)__builtin_nontemporal_load(ei + e);
        unsigned d = (unsigned)__builtin_nontemporal_load(ei + E + e);
        unsigned b = d >> 7, dl = d & 127u;
        unsigned slot = atomicAdd(&gcur[b], 1u);
        packed[slot] = (dl << 17) | s;       // src<2^17, dl<2^7
    }
}

// ---- pass E: per-bucket counting sort -> sorted_src, node_start, dinv ----
__global__ __launch_bounds__(256) void k_sort(const unsigned* __restrict__ packed,
                                              const unsigned* __restrict__ base,
                                              unsigned* __restrict__ sorted,
                                              unsigned* __restrict__ node_start,
                                              float* __restrict__ dinv) {
    __shared__ unsigned cnt[NPB];
    __shared__ unsigned pref[NPB];
    __shared__ unsigned cur[NPB];
    int b = blockIdx.x, t = threadIdx.x;
    if (t < NPB) cnt[t] = 0;
    __syncthreads();
    unsigned e0 = base[b], e1 = base[b + 1];
    for (unsigned e = e0 + t; e < e1; e += 256)
        atomicAdd(&cnt[__builtin_nontemporal_load(packed + e) >> 17], 1u);
    __syncthreads();
    if (t < NPB) pref[t] = cnt[t];
    __syncthreads();
    for (int off = 1; off < NPB; off <<= 1) {
        unsigned u = (t < NPB && t >= off) ? pref[t - off] : 0u;
        __syncthreads();
        if (t < NPB) pref[t] += u;           // inclusive scan
        __syncthreads();
    }
    if (t < NPB) {
        unsigned ex = pref[t] - cnt[t];
        cur[t] = ex;
        int node = b * NPB + t;
        if (node < N) {
            node_start[node] = e0 + ex;
            dinv[node] = rsqrtf((float)cnt[t] + 1.0f);
        }
    }
    if (b == NB - 1 && t == 0) node_start[N] = e1;
    __syncthreads();
    for (unsigned e = e0 + t; e < e1; e += 256) {
        unsigned p = __builtin_nontemporal_load(packed + e);
        unsigned slot = e0 + atomicAdd(&cur[p >> 17], 1u);
        sorted[slot] = p & 0x1FFFFu;
    }
}

// ---- layer1 linear: h1s = fp16(dinv * (x @ W1)) ----
__global__ __launch_bounds__(256) void k_lin1(const float* __restrict__ x,
                                              const float* __restrict__ W1,
                                              const float* __restrict__ dinv,
                                              __half* __restrict__ h1s) {
    __shared__ float W1T[HID][IN_CH + 4];
    __shared__ float xs[16][IN_CH + 4];
    int t = threadIdx.x;
    for (int i = t; i < IN_CH * HID; i += 256) {
        int k = i >> 4, c = i & 15;
        W1T[c][k] = W1[i];
    }
    int rb = blockIdx.x * 16;
    const float4* xblk = (const float4*)(x + (size_t)rb * IN_CH);
    for (int i4 = t; i4 < 16 * IN_CH / 4; i4 += 256) {
        int r = i4 >> 5, c4 = i4 & 31;
        *(float4*)&xs[r][c4 * 4] = xblk[i4];
    }
    __syncthreads();

    int r = t >> 4, c = t & 15;
    int row = rb + r;
    if (row < N) {
        const float4* xr = (const float4*)xs[r];
        const float4* wr = (const float4*)W1T[c];
        float acc = 0.f;
        #pragma unroll
        for (int k4 = 0; k4 < IN_CH / 4; ++k4) {
            float4 a = xr[k4], w = wr[k4];
            acc += a.x * w.x + a.y * w.y + a.z * w.z + a.w * w.w;
        }
        h1s[(size_t)row * HID + c] = __float2half_rn(dinv[row] * acc);
    }
}

__device__ __forceinline__ void accum8(float* acc, const float4& raw) {
    const __half2* hp = (const __half2*)&raw;
    #pragma unroll
    for (int j = 0; j < 4; ++j) {
        float2 f = __half22float2(hp[j]);
        acc[2 * j] += f.x;
        acc[2 * j + 1] += f.y;
    }
}

// ---- layer1 aggregation (wave/node, 2 lanes/edge): ----
// h2s[d] = fp16(dinv*relu(dinv*(sum h1s[src] + h1s[d]) + b1))
__global__ __launch_bounds__(256) void k_agg1(const unsigned* __restrict__ sorted,
                                              const unsigned* __restrict__ ns,
                                              const float* __restrict__ dinv,
                                              const __half* __restrict__ h1s,
                                              const float* __restrict__ b1,
                                              __half* __restrict__ h2s) {
    int wid = (blockIdx.x * 256 + threadIdx.x) >> 6;
    int lane = threadIdx.x & 63;
    int half = lane & 1, eslot = lane >> 1;
    unsigned s0 = ns[wid], s1 = ns[wid + 1];
    float di = dinv[wid];
    float4 bA = *(const float4*)(b1 + half * 8);
    float4 bB = *(const float4*)(b1 + half * 8 + 4);
    float4 selfraw = *(const float4*)(h1s + (size_t)wid * HID + half * 8);

    float acc[8];
    {   // masked self-loop init (only eslot==0 lanes carry it)
        const __half2* hp = (const __half2*)&selfraw;
        float m = (eslot == 0) ? 1.f : 0.f;
        #pragma unroll
        for (int j = 0; j < 4; ++j) {
            float2 f = __half22float2(hp[j]);
            acc[2 * j] = m * f.x;
            acc[2 * j + 1] = m * f.y;
        }
    }
    for (unsigned e = s0 + eslot; e < s1; e += 32) {
        unsigned src = __builtin_nontemporal_load(sorted + e);
        float4 raw = *(const float4*)(h1s + (size_t)src * HID + half * 8);
        accum8(acc, raw);
    }
    #pragma unroll
    for (int off = 2; off < 64; off <<= 1) {
        #pragma unroll
        for (int j = 0; j < 8; ++j) acc[j] += __shfl_xor(acc[j], off, 64);
    }
    if (lane < 2) {
        float bb[8] = {bA.x, bA.y, bA.z, bA.w, bB.x, bB.y, bB.z, bB.w};
        float o[8];
        #pragma unroll
        for (int j = 0; j < 8; ++j)
            o[j] = di * fmaxf(di * acc[j] + bb[j], 0.f);
        float4 ow;
        __half2* op = (__half2*)&ow;
        #pragma unroll
        for (int j = 0; j < 4; ++j)
            op[j] = __float22half2_rn(float2{o[2 * j], o[2 * j + 1]});
        *(float4*)(h2s + (size_t)wid * HID + half * 8) = ow;
    }
}

// ---- layer2 aggregation + fused W2/b2 (wave/node, 2 lanes/edge) ----
__global__ __launch_bounds__(256) void k_agg2(const unsigned* __restrict__ sorted,
                                              const unsigned* __restrict__ ns,
                                              const float* __restrict__ dinv,
                                              const __half* __restrict__ h2s,
                                              const float* __restrict__ W2,
                                              const float* __restrict__ b2,
                                              float* __restrict__ out) {
    __shared__ float W2s[HID * OUT_CH];
    int t = threadIdx.x;
    for (int i = t; i < HID * OUT_CH; i += 256) W2s[i] = W2[i];
    __syncthreads();
    int wid = (blockIdx.x * 256 + t) >> 6;
    int lane = t & 63;
    int half = lane & 1, eslot = lane >> 1;
    unsigned s0 = ns[wid], s1 = ns[wid + 1];
    float di = dinv[wid];
    float bsum = b2[lane];
    float4 selfraw = *(const float4*)(h2s + (size_t)wid * HID + half * 8);

    float acc[8];
    {
        const __half2* hp = (const __half2*)&selfraw;
        float m = (eslot == 0) ? 1.f : 0.f;
        #pragma unroll
        for (int j = 0; j < 4; ++j) {
            float2 f = __half22float2(hp[j]);
            acc[2 * j] = m * f.x;
            acc[2 * j + 1] = m * f.y;
        }
    }
    for (unsigned e = s0 + eslot; e < s1; e += 32) {
        unsigned src = __builtin_nontemporal_load(sorted + e);
        float4 raw = *(const float4*)(h2s + (size_t)src * HID + half * 8);
        accum8(acc, raw);
    }
    #pragma unroll
    for (int off = 2; off < 64; off <<= 1) {
        #pragma unroll
        for (int j = 0; j < 8; ++j) acc[j] += __shfl_xor(acc[j], off, 64);
    }
    // every lane now has the 8-channel totals for its half; fetch the other 8
    int c = lane;
    int rowA = half * 8, rowB = 8 - rowA;
    float sum = bsum;
    #pragma unroll
    for (int j = 0; j < 8; ++j) {
        float v = di * acc[j];
        float o = __shfl_xor(v, 1, 64);
        sum += v * W2s[(rowA + j) * OUT_CH + c] + o * W2s[(rowB + j) * OUT_CH + c];
    }
    out[(size_t)wid * OUT_CH + c] = sum;
}

extern "C" void kernel_launch(void* const* d_in, const int* in_sizes, int n_in,
                              void* d_out, int out_size, void* d_ws, size_t ws_size,
                              hipStream_t stream) {
    const float* x  = (const float*)d_in[0];
    const int*   ei = (const int*)d_in[1];
    const float* W1 = (const float*)d_in[2];
    const float* b1 = (const float*)d_in[3];
    const float* W2 = (const float*)d_in[4];
    const float* b2 = (const float*)d_in[5];
    float* out = (float*)d_out;

    char* ws = (char*)d_ws;
    float*    dinv   = (float*)(ws);                    // N f32
    unsigned* node_start = (unsigned*)(ws + 524288);    // (N+1) u32
    unsigned* tot    = (unsigned*)(ws + 1048576);       // NB u32
    unsigned* base   = (unsigned*)(ws + 1056768);       // NB+1 u32
    unsigned* pbc    = (unsigned*)(ws + 1064960);       // PBLK*NB u32
    unsigned* packed = (unsigned*)(ws + 2097152);       // E u32, dead after k_sort
    __half*   h1s    = (__half*)(ws + 2097152);         // N*16 half — overlays packed
    __half*   h2s    = (__half*)(ws + 5505024);         // N*16 half — overlays packed
    unsigned* sorted = (unsigned*)(ws + 14897152);      // E u32

    k_hist      <<<PBLK, 256, 0, stream>>>(ei, pbc);
    k_scan_cols <<<NB, PBLK, 0, stream>>>(pbc, tot);
    k_scan_tot  <<<1, 1024, 0, stream>>>(tot, base);
    k_partition <<<PBLK, 256, 0, stream>>>(ei, pbc, base, packed);
    k_sort      <<<NB, 256, 0, stream>>>(packed, base, sorted, node_start, dinv);
    k_lin1      <<<(N + 15) / 16, 256, 0, stream>>>(x, W1, dinv, h1s);
    k_agg1      <<<N / 4, 256, 0, stream>>>(sorted, node_start, dinv, h1s, b1, h2s);
    k_agg2      <<<N / 4, 256, 0, stream>>>(sorted, node_start, dinv, h2s, W2, b2, out);
}

// Round 6
// 248.528 us; speedup vs baseline: 1.0017x; 1.0017x over previous
//
#include <hip/hip_runtime.h>
#include <hip/hip_fp16.h>

constexpr int N      = 100000;
constexpr int E      = 3200000;
constexpr int IN_CH  = 128;
constexpr int HID    = 16;
constexpr int OUT_CH = 64;

constexpr int NPB    = 128;                  // nodes per bucket
constexpr int NB     = (N + NPB - 1) / NPB;  // 782 buckets
constexpr int PBLK   = 256;                  // partition blocks
constexpr int CHUNK  = (E + PBLK - 1) / PBLK;

typedef float  nfloat4 __attribute__((ext_vector_type(4)));  // native vec for NT builtins

// ---- pass A: per-block bucket histogram (no global atomics) ----
__global__ __launch_bounds__(256) void k_hist(const int* __restrict__ ei,
                                              unsigned* __restrict__ pbc) {
    __shared__ unsigned cnt[NB];
    int k = blockIdx.x, t = threadIdx.x;
    for (int b = t; b < NB; b += 256) cnt[b] = 0;
    __syncthreads();
    const int* dst = ei + E;
    int e0 = k * CHUNK, e1 = min(e0 + CHUNK, E);
    for (int e = e0 + t; e < e1; e += 256)
        atomicAdd(&cnt[((unsigned)__builtin_nontemporal_load(dst + e)) >> 7], 1u);
    __syncthreads();
    for (int b = t; b < NB; b += 256) pbc[(size_t)k * NB + b] = cnt[b];
}

// ---- pass B: column scan ----
__global__ __launch_bounds__(256) void k_scan_cols(unsigned* __restrict__ pbc,
                                                   unsigned* __restrict__ tot) {
    __shared__ unsigned s[PBLK];
    int b = blockIdx.x, t = threadIdx.x;
    unsigned v = pbc[(size_t)t * NB + b];
    s[t] = v;
    __syncthreads();
    for (int off = 1; off < PBLK; off <<= 1) {
        unsigned u = (t >= off) ? s[t - off] : 0u;
        __syncthreads();
        s[t] += u;
        __syncthreads();
    }
    pbc[(size_t)t * NB + b] = s[t] - v;      // exclusive
    if (t == PBLK - 1) tot[b] = s[t];
}

// ---- pass C: scan bucket totals ----
__global__ __launch_bounds__(1024) void k_scan_tot(const unsigned* __restrict__ tot,
                                                   unsigned* __restrict__ base) {
    __shared__ unsigned s[1024];
    int t = threadIdx.x;
    unsigned v = (t < NB) ? tot[t] : 0u;
    s[t] = v;
    __syncthreads();
    for (int off = 1; off < 1024; off <<= 1) {
        unsigned u = (t >= off) ? s[t - off] : 0u;
        __syncthreads();
        s[t] += u;
        __syncthreads();
    }
    if (t < NB) base[t] = s[t] - v;
    if (t == 1023) base[NB] = s[t];
}

// ---- pass D: partition edges into buckets ----
__global__ __launch_bounds__(256) void k_partition(const int* __restrict__ ei,
                                                   const unsigned* __restrict__ pbc,
                                                   const unsigned* __restrict__ base,
                                                   unsigned* __restrict__ packed) {
    __shared__ unsigned gcur[NB];
    int k = blockIdx.x, t = threadIdx.x;
    for (int b = t; b < NB; b += 256)
        gcur[b] = base[b] + pbc[(size_t)k * NB + b];
    __syncthreads();
    int e0 = k * CHUNK, e1 = min(e0 + CHUNK, E);
    for (int e = e0 + t; e < e1; e += 256) {
        unsigned s = (unsigned)__builtin_nontemporal_load(ei + e);
        unsigned d = (unsigned)__builtin_nontemporal_load(ei + E + e);
        unsigned b = d >> 7, dl = d & 127u;
        unsigned slot = atomicAdd(&gcur[b], 1u);
        packed[slot] = (dl << 17) | s;       // src<2^17, dl<2^7
    }
}

// ---- pass E: per-bucket counting sort -> sorted_src, node_start, dinv ----
__global__ __launch_bounds__(256) void k_sort(const unsigned* __restrict__ packed,
                                              const unsigned* __restrict__ base,
                                              unsigned* __restrict__ sorted,
                                              unsigned* __restrict__ node_start,
                                              float* __restrict__ dinv) {
    __shared__ unsigned cnt[NPB];
    __shared__ unsigned pref[NPB];
    __shared__ unsigned cur[NPB];
    int b = blockIdx.x, t = threadIdx.x;
    if (t < NPB) cnt[t] = 0;
    __syncthreads();
    unsigned e0 = base[b], e1 = base[b + 1];
    for (unsigned e = e0 + t; e < e1; e += 256)
        atomicAdd(&cnt[__builtin_nontemporal_load(packed + e) >> 17], 1u);
    __syncthreads();
    if (t < NPB) pref[t] = cnt[t];
    __syncthreads();
    for (int off = 1; off < NPB; off <<= 1) {
        unsigned u = (t < NPB && t >= off) ? pref[t - off] : 0u;
        __syncthreads();
        if (t < NPB) pref[t] += u;           // inclusive scan
        __syncthreads();
    }
    if (t < NPB) {
        unsigned ex = pref[t] - cnt[t];
        cur[t] = ex;
        int node = b * NPB + t;
        if (node < N) {
            node_start[node] = e0 + ex;
            dinv[node] = rsqrtf((float)cnt[t] + 1.0f);
        }
    }
    if (b == NB - 1 && t == 0) node_start[N] = e1;
    __syncthreads();
    for (unsigned e = e0 + t; e < e1; e += 256) {
        unsigned p = __builtin_nontemporal_load(packed + e);
        unsigned slot = e0 + atomicAdd(&cur[p >> 17], 1u);
        sorted[slot] = p & 0x1FFFFu;
    }
}

// ---- layer1 linear: h1s = fp16(dinv * (x @ W1)) ----
__global__ __launch_bounds__(256) void k_lin1(const float* __restrict__ x,
                                              const float* __restrict__ W1,
                                              const float* __restrict__ dinv,
                                              __half* __restrict__ h1s) {
    __shared__ float W1T[HID][IN_CH + 4];
    __shared__ float xs[16][IN_CH + 4];
    int t = threadIdx.x;
    for (int i = t; i < IN_CH * HID; i += 256) {
        int k = i >> 4, c = i & 15;
        W1T[c][k] = W1[i];
    }
    int rb = blockIdx.x * 16;
    const float4* xblk = (const float4*)(x + (size_t)rb * IN_CH);
    for (int i4 = t; i4 < 16 * IN_CH / 4; i4 += 256) {
        int r = i4 >> 5, c4 = i4 & 31;
        *(float4*)&xs[r][c4 * 4] = xblk[i4];
    }
    __syncthreads();

    int r = t >> 4, c = t & 15;
    int row = rb + r;
    if (row < N) {
        const float4* xr = (const float4*)xs[r];
        const float4* wr = (const float4*)W1T[c];
        float acc = 0.f;
        #pragma unroll
        for (int k4 = 0; k4 < IN_CH / 4; ++k4) {
            float4 a = xr[k4], w = wr[k4];
            acc += a.x * w.x + a.y * w.y + a.z * w.z + a.w * w.w;
        }
        // NT store (as u16 bits): keep reader-critical arrays resident in L2
        __half hv = __float2half_rn(dinv[row] * acc);
        __builtin_nontemporal_store(*(const unsigned short*)&hv,
                                    (unsigned short*)(h1s + (size_t)row * HID + c));
    }
}

__device__ __forceinline__ void accum8(float* acc, const float4& raw) {
    const __half2* hp = (const __half2*)&raw;
    #pragma unroll
    for (int j = 0; j < 4; ++j) {
        float2 f = __half22float2(hp[j]);
        acc[2 * j] += f.x;
        acc[2 * j + 1] += f.y;
    }
}

// ---- layer1 aggregation (wave/node, 2 lanes/edge, 2-deep pipeline) ----
// h2s[d] = fp16(dinv*relu(dinv*(sum h1s[src] + h1s[d]) + b1))
__global__ __launch_bounds__(256) void k_agg1(const unsigned* __restrict__ sorted,
                                              const unsigned* __restrict__ ns,
                                              const float* __restrict__ dinv,
                                              const __half* __restrict__ h1s,
                                              const float* __restrict__ b1,
                                              __half* __restrict__ h2s) {
    int wid = (blockIdx.x * 256 + threadIdx.x) >> 6;
    int lane = threadIdx.x & 63;
    int half = lane & 1, eslot = lane >> 1;
    uint2 nsv = *(const uint2*)(ns + wid);
    unsigned s0 = nsv.x, s1 = nsv.y;
    float di = dinv[wid];
    float4 bA = *(const float4*)(b1 + half * 8);
    float4 bB = *(const float4*)(b1 + half * 8 + 4);
    float4 selfraw = *(const float4*)(h1s + (size_t)wid * HID + half * 8);

    float acc[8];
    {   // masked self-loop init (only eslot==0 lanes carry it)
        const __half2* hp = (const __half2*)&selfraw;
        float m = (eslot == 0) ? 1.f : 0.f;
        #pragma unroll
        for (int j = 0; j < 4; ++j) {
            float2 f = __half22float2(hp[j]);
            acc[2 * j] = m * f.x;
            acc[2 * j + 1] = m * f.y;
        }
    }
    unsigned e = s0 + eslot;
    unsigned nextsrc = (e < s1) ? __builtin_nontemporal_load(sorted + e) : 0u;
    for (; e < s1; e += 32) {
        unsigned src = nextsrc;
        if (e + 32 < s1) nextsrc = __builtin_nontemporal_load(sorted + e + 32);
        float4 raw = *(const float4*)(h1s + (size_t)src * HID + half * 8);
        accum8(acc, raw);
    }
    #pragma unroll
    for (int off = 2; off < 64; off <<= 1) {
        #pragma unroll
        for (int j = 0; j < 8; ++j) acc[j] += __shfl_xor(acc[j], off, 64);
    }
    if (lane < 2) {
        float bb[8] = {bA.x, bA.y, bA.z, bA.w, bB.x, bB.y, bB.z, bB.w};
        float o[8];
        #pragma unroll
        for (int j = 0; j < 8; ++j)
            o[j] = di * fmaxf(di * acc[j] + bb[j], 0.f);
        nfloat4 ow;
        __half2 tmp[4];
        #pragma unroll
        for (int j = 0; j < 4; ++j)
            tmp[j] = __float22half2_rn(float2{o[2 * j], o[2 * j + 1]});
        ow = *(const nfloat4*)tmp;
        // NT store: avoid write-allocate evicting h1s from this XCD's L2
        __builtin_nontemporal_store(ow, (nfloat4*)(h2s + (size_t)wid * HID + half * 8));
    }
}

// ---- layer2 aggregation + fused W2/b2 (wave/node, 2 lanes/edge, pipelined) ----
__global__ __launch_bounds__(256) void k_agg2(const unsigned* __restrict__ sorted,
                                              const unsigned* __restrict__ ns,
                                              const float* __restrict__ dinv,
                                              const __half* __restrict__ h2s,
                                              const float* __restrict__ W2,
                                              const float* __restrict__ b2,
                                              float* __restrict__ out) {
    __shared__ float W2s[HID * OUT_CH];
    int t = threadIdx.x;
    for (int i = t; i < HID * OUT_CH; i += 256) W2s[i] = W2[i];
    __syncthreads();
    int wid = (blockIdx.x * 256 + t) >> 6;
    int lane = t & 63;
    int half = lane & 1, eslot = lane >> 1;
    uint2 nsv = *(const uint2*)(ns + wid);
    unsigned s0 = nsv.x, s1 = nsv.y;
    float di = dinv[wid];
    float bsum = b2[lane];
    float4 selfraw = *(const float4*)(h2s + (size_t)wid * HID + half * 8);

    float acc[8];
    {
        const __half2* hp = (const __half2*)&selfraw;
        float m = (eslot == 0) ? 1.f : 0.f;
        #pragma unroll
        for (int j = 0; j < 4; ++j) {
            float2 f = __half22float2(hp[j]);
            acc[2 * j] = m * f.x;
            acc[2 * j + 1] = m * f.y;
        }
    }
    unsigned e = s0 + eslot;
    unsigned nextsrc = (e < s1) ? __builtin_nontemporal_load(sorted + e) : 0u;
    for (; e < s1; e += 32) {
        unsigned src = nextsrc;
        if (e + 32 < s1) nextsrc = __builtin_nontemporal_load(sorted + e + 32);
        float4 raw = *(const float4*)(h2s + (size_t)src * HID + half * 8);
        accum8(acc, raw);
    }
    #pragma unroll
    for (int off = 2; off < 64; off <<= 1) {
        #pragma unroll
        for (int j = 0; j < 8; ++j) acc[j] += __shfl_xor(acc[j], off, 64);
    }
    // every lane has the 8-channel totals for its half; fetch the other 8
    int c = lane;
    int rowA = half * 8, rowB = 8 - rowA;
    float sum = bsum;
    #pragma unroll
    for (int j = 0; j < 8; ++j) {
        float v = di * acc[j];
        float o = __shfl_xor(v, 1, 64);
        sum += v * W2s[(rowA + j) * OUT_CH + c] + o * W2s[(rowB + j) * OUT_CH + c];
    }
    // NT store: out is never re-read on device; don't evict h2s
    __builtin_nontemporal_store(sum, out + (size_t)wid * OUT_CH + c);
}

extern "C" void kernel_launch(void* const* d_in, const int* in_sizes, int n_in,
                              void* d_out, int out_size, void* d_ws, size_t ws_size,
                              hipStream_t stream) {
    const float* x  = (const float*)d_in[0];
    const int*   ei = (const int*)d_in[1];
    const float* W1 = (const float*)d_in[2];
    const float* b1 = (const float*)d_in[3];
    const float* W2 = (const float*)d_in[4];
    const float* b2 = (const float*)d_in[5];
    float* out = (float*)d_out;

    char* ws = (char*)d_ws;
    float*    dinv   = (float*)(ws);                    // N f32
    unsigned* node_start = (unsigned*)(ws + 524288);    // (N+1) u32
    unsigned* tot    = (unsigned*)(ws + 1048576);       // NB u32
    unsigned* base   = (unsigned*)(ws + 1056768);       // NB+1 u32
    unsigned* pbc    = (unsigned*)(ws + 1064960);       // PBLK*NB u32
    unsigned* packed = (unsigned*)(ws + 2097152);       // E u32, dead after k_sort
    __half*   h1s    = (__half*)(ws + 2097152);         // N*16 half — overlays packed
    __half*   h2s    = (__half*)(ws + 5505024);         // N*16 half — overlays packed
    unsigned* sorted = (unsigned*)(ws + 14897152);      // E u32

    k_hist      <<<PBLK, 256, 0, stream>>>(ei, pbc);
    k_scan_cols <<<NB, PBLK, 0, stream>>>(pbc, tot);
    k_scan_tot  <<<1, 1024, 0, stream>>>(tot, base);
    k_partition <<<PBLK, 256, 0, stream>>>(ei, pbc, base, packed);
    k_sort      <<<NB, 256, 0, stream>>>(packed, base, sorted, node_start, dinv);
    k_lin1      <<<(N + 15) / 16, 256, 0, stream>>>(x, W1, dinv, h1s);
    k_agg1      <<<N / 4, 256, 0, stream>>>(sorted, node_start, dinv, h1s, b1, h2s);
    k_agg2      <<<N / 4, 256, 0, stream>>>(sorted, node_start, dinv, h2s, W2, b2, out);
}

// Round 7
// 216.620 us; speedup vs baseline: 1.1492x; 1.1473x over previous
//
#include <hip/hip_runtime.h>
#include <hip/hip_fp16.h>

constexpr int N      = 100000;
constexpr int E      = 3200000;
constexpr int IN_CH  = 128;
constexpr int HID    = 16;
constexpr int OUT_CH = 64;

constexpr int NPB    = 128;                  // nodes per bucket
constexpr int NB     = (N + NPB - 1) / NPB;  // 782 buckets
constexpr int PBLK   = 256;                  // partition blocks
constexpr int CHUNK  = (E + PBLK - 1) / PBLK;

typedef float nfloat4 __attribute__((ext_vector_type(4)));  // native vec for NT builtins

// ---- pass A: per-block bucket histogram ----
__global__ __launch_bounds__(256) void k_hist(const int* __restrict__ ei,
                                              unsigned* __restrict__ pbc) {
    __shared__ unsigned cnt[NB];
    int k = blockIdx.x, t = threadIdx.x;
    for (int b = t; b < NB; b += 256) cnt[b] = 0;
    __syncthreads();
    const int* dst = ei + E;
    int e0 = k * CHUNK, e1 = min(e0 + CHUNK, E);
    for (int e = e0 + t; e < e1; e += 256)
        atomicAdd(&cnt[((unsigned)__builtin_nontemporal_load(dst + e)) >> 7], 1u);
    __syncthreads();
    for (int b = t; b < NB; b += 256) pbc[(size_t)k * NB + b] = cnt[b];
}

// ---- pass B: column scan ----
__global__ __launch_bounds__(256) void k_scan_cols(unsigned* __restrict__ pbc,
                                                   unsigned* __restrict__ tot) {
    __shared__ unsigned s[PBLK];
    int b = blockIdx.x, t = threadIdx.x;
    unsigned v = pbc[(size_t)t * NB + b];
    s[t] = v;
    __syncthreads();
    for (int off = 1; off < PBLK; off <<= 1) {
        unsigned u = (t >= off) ? s[t - off] : 0u;
        __syncthreads();
        s[t] += u;
        __syncthreads();
    }
    pbc[(size_t)t * NB + b] = s[t] - v;      // exclusive
    if (t == PBLK - 1) tot[b] = s[t];
}

// ---- pass C: scan bucket totals ----
__global__ __launch_bounds__(1024) void k_scan_tot(const unsigned* __restrict__ tot,
                                                   unsigned* __restrict__ base) {
    __shared__ unsigned s[1024];
    int t = threadIdx.x;
    unsigned v = (t < NB) ? tot[t] : 0u;
    s[t] = v;
    __syncthreads();
    for (int off = 1; off < 1024; off <<= 1) {
        unsigned u = (t >= off) ? s[t - off] : 0u;
        __syncthreads();
        s[t] += u;
        __syncthreads();
    }
    if (t < NB) base[t] = s[t] - v;
    if (t == 1023) base[NB] = s[t];
}

// ---- pass D: partition edges into buckets ----
__global__ __launch_bounds__(256) void k_partition(const int* __restrict__ ei,
                                                   const unsigned* __restrict__ pbc,
                                                   const unsigned* __restrict__ base,
                                                   unsigned* __restrict__ packed) {
    __shared__ unsigned gcur[NB];
    int k = blockIdx.x, t = threadIdx.x;
    for (int b = t; b < NB; b += 256)
        gcur[b] = base[b] + pbc[(size_t)k * NB + b];
    __syncthreads();
    int e0 = k * CHUNK, e1 = min(e0 + CHUNK, E);
    for (int e = e0 + t; e < e1; e += 256) {
        unsigned s = (unsigned)__builtin_nontemporal_load(ei + e);
        unsigned d = (unsigned)__builtin_nontemporal_load(ei + E + e);
        unsigned b = d >> 7, dl = d & 127u;
        unsigned slot = atomicAdd(&gcur[b], 1u);
        packed[slot] = (dl << 17) | s;       // src<2^17, dl<2^7
    }
}

// ---- pass E: per-bucket counting sort -> sorted_src, node_start, dinv ----
__global__ __launch_bounds__(256) void k_sort(const unsigned* __restrict__ packed,
                                              const unsigned* __restrict__ base,
                                              unsigned* __restrict__ sorted,
                                              unsigned* __restrict__ node_start,
                                              float* __restrict__ dinv) {
    __shared__ unsigned cnt[NPB];
    __shared__ unsigned pref[NPB];
    __shared__ unsigned cur[NPB];
    int b = blockIdx.x, t = threadIdx.x;
    if (t < NPB) cnt[t] = 0;
    __syncthreads();
    unsigned e0 = base[b], e1 = base[b + 1];
    for (unsigned e = e0 + t; e < e1; e += 256)
        atomicAdd(&cnt[__builtin_nontemporal_load(packed + e) >> 17], 1u);
    __syncthreads();
    if (t < NPB) pref[t] = cnt[t];
    __syncthreads();
    for (int off = 1; off < NPB; off <<= 1) {
        unsigned u = (t < NPB && t >= off) ? pref[t - off] : 0u;
        __syncthreads();
        if (t < NPB) pref[t] += u;           // inclusive scan
        __syncthreads();
    }
    if (t < NPB) {
        unsigned ex = pref[t] - cnt[t];
        cur[t] = ex;
        int node = b * NPB + t;
        if (node < N) {
            node_start[node] = e0 + ex;
            dinv[node] = rsqrtf((float)cnt[t] + 1.0f);
        }
    }
    if (b == NB - 1 && t == 0) node_start[N] = e1;
    __syncthreads();
    for (unsigned e = e0 + t; e < e1; e += 256) {
        unsigned p = __builtin_nontemporal_load(packed + e);
        unsigned slot = e0 + atomicAdd(&cur[p >> 17], 1u);
        sorted[slot] = p & 0x1FFFFu;
    }
}

// ---- layer1 linear: h1s = fp16(dinv * (x @ W1)) ----
__global__ __launch_bounds__(256) void k_lin1(const float* __restrict__ x,
                                              const float* __restrict__ W1,
                                              const float* __restrict__ dinv,
                                              __half* __restrict__ h1s) {
    __shared__ float W1T[HID][IN_CH + 4];
    __shared__ float xs[16][IN_CH + 4];
    int t = threadIdx.x;
    for (int i = t; i < IN_CH * HID; i += 256) {
        int k = i >> 4, c = i & 15;
        W1T[c][k] = W1[i];
    }
    int rb = blockIdx.x * 16;
    const float4* xblk = (const float4*)(x + (size_t)rb * IN_CH);
    for (int i4 = t; i4 < 16 * IN_CH / 4; i4 += 256) {
        int r = i4 >> 5, c4 = i4 & 31;
        *(float4*)&xs[r][c4 * 4] = xblk[i4];
    }
    __syncthreads();

    int r = t >> 4, c = t & 15;
    int row = rb + r;
    const float4* xr = (const float4*)xs[r];
    const float4* wr = (const float4*)W1T[c];
    float acc = 0.f;
    #pragma unroll
    for (int k4 = 0; k4 < IN_CH / 4; ++k4) {
        float4 a = xr[k4], w = wr[k4];
        acc += a.x * w.x + a.y * w.y + a.z * w.z + a.w * w.w;
    }
    __half hv = __float2half_rn(dinv[row] * acc);
    __builtin_nontemporal_store(*(const unsigned short*)&hv,
                                (unsigned short*)(h1s + (size_t)row * HID + c));
}

__device__ __forceinline__ void accum8(float* acc, const float4& raw) {
    const __half2* hp = (const __half2*)&raw;
    #pragma unroll
    for (int j = 0; j < 4; ++j) {
        float2 f = __half22float2(hp[j]);
        acc[2 * j] += f.x;
        acc[2 * j + 1] += f.y;
    }
}

// ================== NEW aggregation: 8 nodes/wave, 8 lanes/node =================
// lane = nw*8 + eslot*2 + half;  nw in [0,8), eslot in [0,4), half in {0,1}
// gather-sum over in-edges; butterfly over eslot only (2 steps x 8 regs / wave).

// ---- layer1 agg: h2s[d] = fp16(dinv*relu(dinv*(sum h1s[src] + h1s[d]) + b1)) ----
__global__ __launch_bounds__(256) void k_agg1(const unsigned* __restrict__ sorted,
                                              const unsigned* __restrict__ ns,
                                              const float* __restrict__ dinv,
                                              const __half* __restrict__ h1s,
                                              const float* __restrict__ b1,
                                              __half* __restrict__ h2s) {
    int t = threadIdx.x;
    int wave = (blockIdx.x << 2) + (t >> 6);     // global wave id
    int lane = t & 63;
    int nw = lane >> 3, slot = lane & 7;
    int eslot = slot >> 1, half = slot & 1;
    int wid = (wave << 3) + nw;                  // node, uniform per 8-lane group
    unsigned s0 = ns[wid], s1 = ns[wid + 1];
    float di = dinv[wid];
    float4 bb = *(const float4*)(b1 + half * 8);
    float4 bb2 = *(const float4*)(b1 + half * 8 + 4);
    float4 selfraw = *(const float4*)(h1s + (size_t)wid * HID + half * 8);

    float acc[8];
    {   // self-loop carried by eslot==0 lanes
        const __half2* hp = (const __half2*)&selfraw;
        float m = (eslot == 0) ? 1.f : 0.f;
        #pragma unroll
        for (int j = 0; j < 4; ++j) {
            float2 f = __half22float2(hp[j]);
            acc[2 * j] = m * f.x;
            acc[2 * j + 1] = m * f.y;
        }
    }
    unsigned e = s0 + eslot;
    bool valid = e < s1;
    unsigned src = valid ? __builtin_nontemporal_load(sorted + e) : 0u;
    while (__any((int)valid)) {
        unsigned e2 = e + 4;
        bool valid2 = e2 < s1;
        unsigned src2 = valid2 ? __builtin_nontemporal_load(sorted + e2) : 0u;
        if (valid) {
            float4 raw = *(const float4*)(h1s + (size_t)src * HID + half * 8);
            accum8(acc, raw);
        }
        e = e2; valid = valid2; src = src2;
    }
    #pragma unroll
    for (int j = 0; j < 8; ++j) acc[j] += __shfl_xor(acc[j], 2, 64);
    #pragma unroll
    for (int j = 0; j < 8; ++j) acc[j] += __shfl_xor(acc[j], 4, 64);

    if (eslot == 0) {
        float bv[8] = {bb.x, bb.y, bb.z, bb.w, bb2.x, bb2.y, bb2.z, bb2.w};
        __half2 tmp[4];
        #pragma unroll
        for (int j = 0; j < 4; ++j) {
            float o0 = di * fmaxf(di * acc[2 * j] + bv[2 * j], 0.f);
            float o1 = di * fmaxf(di * acc[2 * j + 1] + bv[2 * j + 1], 0.f);
            tmp[j] = __float22half2_rn(float2{o0, o1});
        }
        nfloat4 ow = *(const nfloat4*)tmp;
        __builtin_nontemporal_store(ow, (nfloat4*)(h2s + (size_t)wid * HID + half * 8));
    }
}

// ---- layer2 agg (gather only): hag[d] = fp16(dinv[d]*(sum h2s[src] + h2s[d])) ----
__global__ __launch_bounds__(256) void k_agg2(const unsigned* __restrict__ sorted,
                                              const unsigned* __restrict__ ns,
                                              const float* __restrict__ dinv,
                                              const __half* __restrict__ h2s,
                                              __half* __restrict__ hag) {
    int t = threadIdx.x;
    int wave = (blockIdx.x << 2) + (t >> 6);
    int lane = t & 63;
    int nw = lane >> 3, slot = lane & 7;
    int eslot = slot >> 1, half = slot & 1;
    int wid = (wave << 3) + nw;
    unsigned s0 = ns[wid], s1 = ns[wid + 1];
    float di = dinv[wid];
    float4 selfraw = *(const float4*)(h2s + (size_t)wid * HID + half * 8);

    float acc[8];
    {
        const __half2* hp = (const __half2*)&selfraw;
        float m = (eslot == 0) ? 1.f : 0.f;
        #pragma unroll
        for (int j = 0; j < 4; ++j) {
            float2 f = __half22float2(hp[j]);
            acc[2 * j] = m * f.x;
            acc[2 * j + 1] = m * f.y;
        }
    }
    unsigned e = s0 + eslot;
    bool valid = e < s1;
    unsigned src = valid ? __builtin_nontemporal_load(sorted + e) : 0u;
    while (__any((int)valid)) {
        unsigned e2 = e + 4;
        bool valid2 = e2 < s1;
        unsigned src2 = valid2 ? __builtin_nontemporal_load(sorted + e2) : 0u;
        if (valid) {
            float4 raw = *(const float4*)(h2s + (size_t)src * HID + half * 8);
            accum8(acc, raw);
        }
        e = e2; valid = valid2; src = src2;
    }
    #pragma unroll
    for (int j = 0; j < 8; ++j) acc[j] += __shfl_xor(acc[j], 2, 64);
    #pragma unroll
    for (int j = 0; j < 8; ++j) acc[j] += __shfl_xor(acc[j], 4, 64);

    if (eslot == 0) {
        __half2 tmp[4];
        #pragma unroll
        for (int j = 0; j < 4; ++j)
            tmp[j] = __float22half2_rn(float2{di * acc[2 * j], di * acc[2 * j + 1]});
        nfloat4 ow = *(const nfloat4*)tmp;
        __builtin_nontemporal_store(ow, (nfloat4*)(hag + (size_t)wid * HID + half * 8));
    }
}

// ---- layer2 linear: out = hag @ W2 + b2 (dense, coalesced) ----
__global__ __launch_bounds__(256) void k_lin2(const __half* __restrict__ hag,
                                              const float* __restrict__ W2,
                                              const float* __restrict__ b2,
                                              float* __restrict__ out) {
    __shared__ float W2s[HID * OUT_CH];   // 4 KB
    __shared__ float as[16][HID];
    int t = threadIdx.x;
    for (int i = t; i < HID * OUT_CH; i += 256) W2s[i] = W2[i];
    int rb = blockIdx.x * 16;
    as[t >> 4][t & 15] = __half2float(hag[(size_t)rb * HID + t]);
    __syncthreads();

    int r = t >> 4;
    int c4 = (t & 15) * 4;
    int row = rb + r;
    float4 acc = *(const float4*)&b2[c4];
    #pragma unroll
    for (int k = 0; k < HID; ++k) {
        float a = as[r][k];
        const float* w = &W2s[k * OUT_CH + c4];
        acc.x += a * w[0]; acc.y += a * w[1]; acc.z += a * w[2]; acc.w += a * w[3];
    }
    nfloat4 o = {acc.x, acc.y, acc.z, acc.w};
    __builtin_nontemporal_store(o, (nfloat4*)(out + (size_t)row * OUT_CH + c4));
}

extern "C" void kernel_launch(void* const* d_in, const int* in_sizes, int n_in,
                              void* d_out, int out_size, void* d_ws, size_t ws_size,
                              hipStream_t stream) {
    const float* x  = (const float*)d_in[0];
    const int*   ei = (const int*)d_in[1];
    const float* W1 = (const float*)d_in[2];
    const float* b1 = (const float*)d_in[3];
    const float* W2 = (const float*)d_in[4];
    const float* b2 = (const float*)d_in[5];
    float* out = (float*)d_out;

    char* ws = (char*)d_ws;
    float*    dinv   = (float*)(ws);                    // N f32
    unsigned* node_start = (unsigned*)(ws + 524288);    // (N+1) u32
    unsigned* tot    = (unsigned*)(ws + 1048576);       // NB u32
    unsigned* base   = (unsigned*)(ws + 1056768);       // NB+1 u32
    unsigned* pbc    = (unsigned*)(ws + 1064960);       // PBLK*NB u32
    unsigned* packed = (unsigned*)(ws + 2097152);       // E u32, dead after k_sort
    __half*   h1s    = (__half*)(ws + 2097152);         // 3.2MB — overlays packed
    __half*   h2s    = (__half*)(ws + 5505024);         // 3.2MB — overlays packed
    __half*   hag    = (__half*)(ws + 8912896);         // 3.2MB — overlays packed
    unsigned* sorted = (unsigned*)(ws + 14897152);      // E u32

    k_hist      <<<PBLK, 256, 0, stream>>>(ei, pbc);
    k_scan_cols <<<NB, PBLK, 0, stream>>>(pbc, tot);
    k_scan_tot  <<<1, 1024, 0, stream>>>(tot, base);
    k_partition <<<PBLK, 256, 0, stream>>>(ei, pbc, base, packed);
    k_sort      <<<NB, 256, 0, stream>>>(packed, base, sorted, node_start, dinv);
    k_lin1      <<<N / 16, 256, 0, stream>>>(x, W1, dinv, h1s);
    k_agg1      <<<N / 32, 256, 0, stream>>>(sorted, node_start, dinv, h1s, b1, h2s);
    k_agg2      <<<N / 32, 256, 0, stream>>>(sorted, node_start, dinv, h2s, hag);
    k_lin2      <<<N / 16, 256, 0, stream>>>(hag, W2, b2, out);
}